// Round 3
// baseline (217.503 us; speedup 1.0000x reference)
//
#include <hip/hip_runtime.h>
#include <hip/hip_fp16.h>

#define NN 100000
#define NE 1600000
#define D  64

#define B1     1024        // scatter blocks: 4 blocks per CU
#define BSH    9           // coarse bin = dst >> 9  (512 nodes per bin)
#define BMSK   511
#define NB     196         // ceil(NN / 512)
#define STRIDE 16256       // ebuf slots per bin (mean 8163, ~90 sigma headroom)

typedef __attribute__((ext_vector_type(8))) _Float16 f16x8;
typedef __attribute__((ext_vector_type(4))) float    f32x4;

// ---------- fused count + alloc + scatter ----------
// pass1: cache this thread's edges in registers, count bins in LDS.
// alloc: one global atomicAdd per bin per block reserves space in the bin's
//        fixed-stride ebuf region.  pass2: write cached edges.
__global__ __launch_bounds__(256) void k_scatter_fused(
    const int* __restrict__ src, const int* __restrict__ dst,
    int* __restrict__ gcnt, unsigned* __restrict__ ebuf)
{
    __shared__ int h[NB];
    int t = threadIdx.x, blk = blockIdx.x;
    for (int i = t; i < NB; i += 256) h[i] = 0;
    __syncthreads();
    unsigned v[7]; int bn[7]; int cntl = 0;
    int e = blk * 256 + t;
#pragma unroll
    for (int i = 0; i < 7; ++i, e += B1 * 256) {
        if (e < NE) {
            int d = dst[e];
            int s = src[e];
            int b = d >> BSH;
            v[i] = ((unsigned)s << BSH) | (unsigned)(d & BMSK);
            bn[i] = b;
            atomicAdd(&h[b], 1);
            cntl = i + 1;
        }
    }
    __syncthreads();
    for (int i = t; i < NB; i += 256)
        h[i] = atomicAdd(&gcnt[i], h[i]);        // h becomes this block's cursor
    __syncthreads();
#pragma unroll
    for (int i = 0; i < 7; ++i) {
        if (i < cntl) {
            int b = bn[i];
            int p = atomicAdd(&h[b], 1);         // LDS atomic
            ebuf[b * STRIDE + p] = v[i];
        }
    }
}

// ---------- exclusive scan of 196 bin counts ----------
__global__ __launch_bounds__(256) void k_scan196(const int* __restrict__ gcnt,
                                                 int* __restrict__ binoff) {
    __shared__ int ps[256];
    int t = threadIdx.x;
    int v = (t < NB) ? gcnt[t] : 0;
    ps[t] = v;
    __syncthreads();
    for (int off = 1; off < 256; off <<= 1) {
        int u = (t >= off) ? ps[t - off] : 0;
        __syncthreads();
        ps[t] += u;
        __syncthreads();
    }
    if (t < NB) binoff[t] = ps[t] - v;            // exclusive bin start
    if (t == NB - 1) binoff[NB] = ps[t];          // == NE
}

// ---------- per-bin exact CSR, all in LDS (one node per thread) ----------
__global__ __launch_bounds__(512) void k_build(
    const int* __restrict__ gcnt, const int* __restrict__ binoff,
    const unsigned* __restrict__ ebuf,
    int* __restrict__ rs, float* __restrict__ dinv, int* __restrict__ bucket)
{
    __shared__ int c[512];
    __shared__ int ps[512];
    int t = threadIdx.x, b = blockIdx.x;
    int e0s = b * STRIDE;                         // ebuf source base
    int cnt = gcnt[b];
    int g0  = binoff[b];                          // bucket dest base
    c[t] = 0;
    __syncthreads();
    for (int e = t; e < cnt; e += 512)
        atomicAdd(&c[ebuf[e0s + e] & BMSK], 1);
    __syncthreads();
    int a = c[t];
    ps[t] = a;
    __syncthreads();
    for (int off = 1; off < 512; off <<= 1) {
        int u = (t >= off) ? ps[t - off] : 0;
        __syncthreads();
        ps[t] += u;
        __syncthreads();
    }
    int p = g0 + ps[t] - a;                       // global row start in bucket
    int node = (b << BSH) + t;
    if (node < NN) { rs[node] = p; dinv[node] = rsqrtf((float)(a + 1)); }
    if (b == NB - 1 && t == 0) rs[NN] = NE;
    __syncthreads();
    c[t] = p;                                     // cursors (global positions)
    __syncthreads();
    for (int e = t; e < cnt; e += 512) {
        unsigned u = ebuf[e0s + e];
        int pp = atomicAdd(&c[u & BMSK], 1);      // LDS atomic
        bucket[pp] = (int)(u >> BSH);
    }
}

// ---------- fused MFMA GEMMs: blocks [0,half): g = half(x@Wg * dinv)
//                              blocks [half,2*half): out = pos@Wp + bg + bp
// wave = 16 rows x 64 cols; A-frag: row=lane&15, k=(lane>>4)*8+j (contig 16B);
// C/D: col=lane&15, row=(lane>>4)*4+reg ----------
__global__ __launch_bounds__(256) void k_mm(
    const float* __restrict__ x, const float* __restrict__ Wg,
    const float* __restrict__ dinv, __half* __restrict__ g,
    const float* __restrict__ pos, const float* __restrict__ Wp,
    const float* __restrict__ bg, const float* __restrict__ bp,
    float* __restrict__ out)
{
    __shared__ __align__(16) _Float16 Wt[64][64];   // Wt[n][k] = W[k][n]
    int t = threadIdx.x;
    int lane = t & 63;
    int wid = t >> 6;
    int half_grid = gridDim.x >> 1;
    bool job2 = blockIdx.x >= half_grid;
    int blk = job2 ? (blockIdx.x - half_grid) : blockIdx.x;
    const float* A = job2 ? pos : x;
    const float* W = job2 ? Wp : Wg;

    // zero-pad row g[NN] (gather's invalid-edge target)
    if (blockIdx.x == 0 && t < 64) g[(long)NN * D + t] = __float2half(0.f);

    for (int i = t; i < 64 * 64; i += 256) {
        int k = i >> 6, n = i & 63;
        Wt[n][k] = (_Float16)W[i];
    }
    __syncthreads();

    int lr = lane & 15;        // A-row / C-col within tile
    int lg = lane >> 4;        // k-group / C-row-group
    int kofs = lg * 8;

    f16x8 b[4][2];             // hoisted B frags: [col-tile][k-tile]
#pragma unroll
    for (int n = 0; n < 4; ++n)
#pragma unroll
        for (int kt = 0; kt < 2; ++kt)
            b[n][kt] = *(const f16x8*)&Wt[n * 16 + lr][kt * 32 + kofs];

    float bsum[4] = {0.f, 0.f, 0.f, 0.f};
    if (job2) {
#pragma unroll
        for (int n = 0; n < 4; ++n) {
            int cc = n * 16 + lr;
            bsum[n] = bg[cc] + bp[cc];
        }
    }

    for (int rb0 = blk * 64; rb0 < NN; rb0 += half_grid * 64) {
        int rb = rb0 + wid * 16;
        int arow = rb + lr;
        int arc = arow < NN ? arow : NN - 1;
        const float4* ap = (const float4*)(A + (long)arc * 64 + kofs);
        float4 p0 = ap[0], p1 = ap[1], p2 = ap[8], p3 = ap[9];
        f16x8 a0, a1;
        a0[0] = (_Float16)p0.x; a0[1] = (_Float16)p0.y;
        a0[2] = (_Float16)p0.z; a0[3] = (_Float16)p0.w;
        a0[4] = (_Float16)p1.x; a0[5] = (_Float16)p1.y;
        a0[6] = (_Float16)p1.z; a0[7] = (_Float16)p1.w;
        a1[0] = (_Float16)p2.x; a1[1] = (_Float16)p2.y;
        a1[2] = (_Float16)p2.z; a1[3] = (_Float16)p2.w;
        a1[4] = (_Float16)p3.x; a1[5] = (_Float16)p3.y;
        a1[6] = (_Float16)p3.z; a1[7] = (_Float16)p3.w;

        f32x4 z = {0.f, 0.f, 0.f, 0.f};
        f32x4 acc[4] = {z, z, z, z};
#pragma unroll
        for (int n = 0; n < 4; ++n) {
            acc[n] = __builtin_amdgcn_mfma_f32_16x16x32_f16(a0, b[n][0], acc[n], 0, 0, 0);
            acc[n] = __builtin_amdgcn_mfma_f32_16x16x32_f16(a1, b[n][1], acc[n], 0, 0, 0);
        }

        int orow0 = rb + lg * 4;
        if (!job2) {
#pragma unroll
            for (int r = 0; r < 4; ++r) {
                int row = orow0 + r;
                if (row < NN) {
                    float di = dinv[row];
#pragma unroll
                    for (int n = 0; n < 4; ++n)
                        g[(long)row * D + n * 16 + lr] = __float2half(acc[n][r] * di);
                }
            }
        } else {
#pragma unroll
            for (int r = 0; r < 4; ++r) {
                int row = orow0 + r;
                if (row < NN) {
#pragma unroll
                    for (int n = 0; n < 4; ++n)
                        out[(long)row * D + n * 16 + lr] = acc[n][r] + bsum[n];
                }
            }
        }
    }
}

// ---------- gather: wave per node, zero-row padding, uniform inner loop ----------
__global__ __launch_bounds__(256) void k_gather(
    const int* __restrict__ rs, const int* __restrict__ bucket,
    const float* __restrict__ dinv, const __half* __restrict__ g,
    float* __restrict__ out)
{
    int lane = threadIdx.x & 63;
    int f = lane & 7;                 // 16B granule within 128B row
    int grp = lane >> 3;              // 8 edges per wave-instruction
    int w0 = (blockIdx.x << 2) + (threadIdx.x >> 6);
    int nw = gridDim.x << 2;
    const uint4* gq = (const uint4*)g;   // row = 8 uint4 granules (128B aligned)

    for (int n0 = w0; n0 < NN; n0 += nw) {
        int node = __builtin_amdgcn_readfirstlane(n0);
        int r0 = rs[node], r1 = rs[node + 1];
        float a0 = 0.f, a1 = 0.f, a2 = 0.f, a3 = 0.f;
        float a4 = 0.f, a5 = 0.f, a6 = 0.f, a7 = 0.f;
        for (int base = r0; base < r1; base += 64) {
            int rem = r1 - base;
            int nl = rem < 64 ? rem : 64;
            int sl = (lane < nl) ? bucket[base + lane] : NN;  // pad -> zero row
            int NG = (nl + 7) >> 3;                           // wave-uniform
#pragma unroll 4
            for (int c = 0; c < NG; ++c) {
                int s = __shfl(sl, c * 8 + grp);
                uint4 u = gq[(long)s * 8 + f];
                __half2 h0 = *(__half2*)&u.x, h1 = *(__half2*)&u.y;
                __half2 h2 = *(__half2*)&u.z, h3 = *(__half2*)&u.w;
                a0 += __low2float(h0); a1 += __high2float(h0);
                a2 += __low2float(h1); a3 += __high2float(h1);
                a4 += __low2float(h2); a5 += __high2float(h2);
                a6 += __low2float(h3); a7 += __high2float(h3);
            }
        }
        // reduce across the 8 edge-groups (lane bits 3,4,5)
#pragma unroll
        for (int mask = 8; mask <= 32; mask <<= 1) {
            a0 += __shfl_xor(a0, mask); a1 += __shfl_xor(a1, mask);
            a2 += __shfl_xor(a2, mask); a3 += __shfl_xor(a3, mask);
            a4 += __shfl_xor(a4, mask); a5 += __shfl_xor(a5, mask);
            a6 += __shfl_xor(a6, mask); a7 += __shfl_xor(a7, mask);
        }
        // epilogue: 16 lanes rmw the full 256B out row, fully coalesced
        if (lane < 16) {
            int ff = lane & 7, hs = lane >> 3;
            uint4 u = gq[(long)node * 8 + ff];               // self row granule
            __half2 s0 = hs ? *(__half2*)&u.z : *(__half2*)&u.x;
            __half2 s1 = hs ? *(__half2*)&u.w : *(__half2*)&u.y;
            float b0 = hs ? a4 : a0, b1 = hs ? a5 : a1;
            float b2 = hs ? a6 : a2, b3 = hs ? a7 : a3;
            float di = dinv[node];
            float4* op = (float4*)(out + (long)node * D) + (ff * 2 + hs);
            float4 o = *op;
            o.x += (b0 + __low2float(s0)) * di;
            o.y += (b1 + __high2float(s0)) * di;
            o.z += (b2 + __low2float(s1)) * di;
            o.w += (b3 + __high2float(s1)) * di;
            *op = o;
        }
    }
}

extern "C" void kernel_launch(void* const* d_in, const int* in_sizes, int n_in,
                              void* d_out, int out_size, void* d_ws, size_t ws_size,
                              hipStream_t stream) {
    const float* x   = (const float*)d_in[0];
    const int*   ei  = (const int*)d_in[1];   // [2, NE] int32
    const float* pos = (const float*)d_in[2];
    const float* Wg  = (const float*)d_in[3];
    const float* bg  = (const float*)d_in[4];
    const float* Wp  = (const float*)d_in[5];
    const float* bp  = (const float*)d_in[6];
    float* out = (float*)d_out;

    const int* src = ei;
    const int* dst = ei + NE;

    // ws layout (~20.0 MiB):
    //   [0)            g[(NN+1)*D] half  (128B-aligned rows; row NN = zeros)
    //                  ebuf[NB*STRIDE] u32 ALIASES g  (ebuf dead after k_build,
    //                                                  g born in k_mm)
    //   [12,800,256)   bucket[NE] | rs[NN+4] | dinv[NN] | gcnt[NB] | binoff[NB+1]
    char* Wb = (char*)d_ws;
    __half*   g      = (__half*)Wb;
    unsigned* ebuf   = (unsigned*)Wb;             // alias, see above
    int*      bucket = (int*)(Wb + 12800256);
    int*      rs     = bucket + NE;
    float*    dinv   = (float*)(rs + NN + 4);
    int*      gcnt   = (int*)(dinv + NN);
    int*      binoff = gcnt + NB;

    hipMemsetAsync(gcnt, 0, NB * sizeof(int), stream);
    hipLaunchKernelGGL(k_scatter_fused, dim3(B1),   dim3(256), 0, stream,
                       src, dst, gcnt, ebuf);
    hipLaunchKernelGGL(k_scan196,       dim3(1),    dim3(256), 0, stream, gcnt, binoff);
    hipLaunchKernelGGL(k_build,         dim3(NB),   dim3(512), 0, stream,
                       gcnt, binoff, ebuf, rs, dinv, bucket);
    hipLaunchKernelGGL(k_mm,            dim3(1564), dim3(256), 0, stream,
                       x, Wg, dinv, g, pos, Wp, bg, bp, out);
    hipLaunchKernelGGL(k_gather,        dim3(2048), dim3(256), 0, stream,
                       rs, bucket, dinv, g, out);
}